// Round 12
// baseline (465.673 us; speedup 1.0000x reference)
//
#include <hip/hip_runtime.h>
#include <stdint.h>

#define K_DIM 4096
#define N_DIM 11008
#define NCOL  1376   // N/8

typedef __attribute__((ext_vector_type(4))) float  f32x4;
typedef __attribute__((ext_vector_type(8))) __bf16 bf16x8;

__device__ __forceinline__ void gload_lds16(const void* g, void* l) {
  __builtin_amdgcn_global_load_lds((const __attribute__((address_space(1))) void*)g,
                                   (__attribute__((address_space(3))) void*)l,
                                   16, 0, 0);
}

// ---------- prologue: AWQ dequant -> Wt bf16 [N][K] (transposed via LDS) ----------
__global__ void __launch_bounds__(256) dequant_kernel(const int* __restrict__ qw,
                                                      const int* __restrict__ qz,
                                                      const float* __restrict__ sc,
                                                      __bf16* __restrict__ wt) {
  constexpr int SH[8] = {0, 16, 4, 20, 8, 24, 12, 28};  // AWQ [0,4,1,5,2,6,3,7]*4
  __shared__ __bf16 tile[64][72];
  const int bid = blockIdx.x;
  const int tk = bid & 63;
  const int tn = bid >> 6;
  const int k0 = tk * 64;
  const int c0 = tn * 8;
  const int t = threadIdx.x;
#pragma unroll
  for (int r = 0; r < 2; ++r) {
    int idx = r * 256 + t;
    int kk = idx >> 3;
    int cc = idx & 7;
    int k = k0 + kk;
    int c = c0 + cc;
    uint32_t q  = (uint32_t)qw[(size_t)k * NCOL + c];
    int g = k >> 7;
    uint32_t zq = (uint32_t)qz[(size_t)g * NCOL + c];
    const float* s = sc + (size_t)g * N_DIM + (size_t)c * 8;
#pragma unroll
    for (int j = 0; j < 8; ++j) {
      int wv = (int)((q >> SH[j]) & 15u) - (int)((zq >> SH[j]) & 15u);
      tile[cc * 8 + j][kk] = (__bf16)((float)wv * s[j]);
    }
  }
  __syncthreads();
  const int n0 = tn * 64;
#pragma unroll
  for (int r = 0; r < 2; ++r) {
    int idx = r * 256 + t;
    int row = idx >> 3;
    int kc = idx & 7;
    bf16x8 v = *(const bf16x8*)&tile[row][kc * 8];
    *(bf16x8*)(wt + (size_t)(n0 + row) * K_DIM + k0 + kc * 8) = v;
  }
}

// ---------- main GEMM: 128x128 tile, BK=64, fused fp32->bf16 A-staging ----------
// R7 chassis (best measured: 195us GEMM, 43% MfmaUtil = structural plateau of
// steady(waves/CU) x eff(grid): max(0.672x64%, 0.896x48%) = 43% -- R1-R11).
// Change: A is staged straight from x (fp32): per thread 8x f32x4 load -> cvt
// -> 4x swizzled ds_write_b128. Kills the convert_x dispatch + Aw HBM
// round-trip (~8us). B keeps gload_lds DMA, issued FIRST so the DMA runs
// under A's load-latency + cvt VALU. Swizzle moves to the A write side
// (reg-staging permits it; rule #21: both-sides consistency kept -- compute
// side unchanged from R7, 0 bank conflicts R1-R11).
// LDS 32KB static -> cap is regs: target <=106 VGPR + 64 AGPR -> 3 waves/SIMD
// -> 3 blk/CU, 12 waves/CU, eff 0.896.
__global__ void __launch_bounds__(256, 3) wq_gemm_kernel(
    const float* __restrict__ Xf,    // [M][K] fp32
    const __bf16* __restrict__ Wt,   // [N][K] bf16
    const float* __restrict__ bias,
    float* __restrict__ out,
    const int Mblk)
{
  __shared__ char As[16384];   // 128 rows x 64 bf16 (128B rows), granule-swizzled
  __shared__ char Bs[16384];

  const int nwg = gridDim.x;
  int bid = blockIdx.x;
  if ((nwg & 7) == 0) {                 // XCD-aware swizzle (1376 % 8 == 0, bijective)
    const int cpx = nwg >> 3;
    bid = (bid & 7) * cpx + (bid >> 3);
  }
  const int bm = bid % Mblk;            // m-fastest: XCD chunk reuses B panels in L2
  const int bn = bid / Mblk;
  const int m0 = bm * 128;
  const int n0 = bn * 128;

  const int t = threadIdx.x;
  const int lane = t & 63;
  const int w = t >> 6;      // 0..3
  const int wr = w >> 1;     // 0..1  (M half)
  const int wc = w & 1;      // 0..1  (N half)
  const int lrow = lane & 15;
  const int lk = lane >> 4;

  // A fused staging: thread covers row ar = t>>1, k-half ah = t&1 (32 cols).
  const int ar = t >> 1;
  const int ah = t & 1;
  const float* xp = Xf + (size_t)(m0 + ar) * K_DIM + ah * 32;
  char* adst = As + ar * 128;

  // B DMA staging (R7-verified): round i covers rows i*32..i*32+31;
  // source granule gl = (t&7)^((t>>3)&7); dest linear cid*16.
  const int gl = (t & 7) ^ ((t >> 3) & 7);
  const uint32_t off0 = (uint32_t)(t >> 3) * K_DIM + (uint32_t)gl * 8;
  const __bf16* pB = Wt + (size_t)n0 * K_DIM + off0;
  const int w1024 = w * 1024;

  f32x4 acc[4][4];
#pragma unroll
  for (int i = 0; i < 4; ++i)
#pragma unroll
    for (int j = 0; j < 4; ++j) acc[i][j] = (f32x4){0.f, 0.f, 0.f, 0.f};

  // compute-side bases (unchanged from R7; row&7 == lrow&7)
  const char* abase = As + (wr * 64 + lrow) * 128;
  const char* bbase = Bs + (wc * 64 + lrow) * 128;
  const int gk0 = (lk ^ (lrow & 7)) << 4;        // kk=0 granule byte offset
  const int gk1 = ((4 + lk) ^ (lrow & 7)) << 4;  // kk=1

  for (int kt = 0; kt < 64; ++kt) {
    __syncthreads();   // previous tile's compute done; LDS reusable
    // B: 4 DMA rounds, issued first (overlap with A load+cvt below)
#pragma unroll
    for (int i = 0; i < 4; ++i)
      gload_lds16(pB + (size_t)i * (32 * K_DIM), Bs + i * 4096 + w1024);
    pB += 64;
    // A: fp32 load -> bf16 cvt -> swizzled ds_write (4 granules of 8 elems)
#pragma unroll
    for (int g = 0; g < 4; ++g) {
      const f32x4 u0 = *(const f32x4*)(xp + g * 8);
      const f32x4 u1 = *(const f32x4*)(xp + g * 8 + 4);
      bf16x8 o;
      o[0] = (__bf16)u0[0]; o[1] = (__bf16)u0[1];
      o[2] = (__bf16)u0[2]; o[3] = (__bf16)u0[3];
      o[4] = (__bf16)u1[0]; o[5] = (__bf16)u1[1];
      o[6] = (__bf16)u1[2]; o[7] = (__bf16)u1[3];
      const int gp = (ah * 4 + g) ^ (ar & 7);
      *(bf16x8*)(adst + (gp << 4)) = o;
    }
    xp += 64;
    __syncthreads();   // drains vmcnt (B DMA) + lgkmcnt (A writes)

#pragma unroll
    for (int kk = 0; kk < 2; ++kk) {
      const int g = kk ? gk1 : gk0;
      bf16x8 av[4], bv[4];
#pragma unroll
      for (int m = 0; m < 4; ++m) av[m] = *(const bf16x8*)(abase + m * 2048 + g);
#pragma unroll
      for (int n = 0; n < 4; ++n) bv[n] = *(const bf16x8*)(bbase + n * 2048 + g);
#pragma unroll
      for (int m = 0; m < 4; ++m)
#pragma unroll
        for (int n = 0; n < 4; ++n)
          acc[m][n] = __builtin_amdgcn_mfma_f32_16x16x32_bf16(av[m], bv[n], acc[m][n], 0, 0, 0);
    }
  }

  // epilogue: C/D layout col=lane&15, row=(lane>>4)*4+reg (m89-verified, R1-R11-passed)
  const int orow0 = m0 + wr * 64 + lk * 4;
  const int ocol0 = n0 + wc * 64 + lrow;
#pragma unroll
  for (int n = 0; n < 4; ++n) {
    const int col = ocol0 + n * 16;
    const float bv = bias[col];
#pragma unroll
    for (int m = 0; m < 4; ++m) {
      float* po = out + (size_t)(orow0 + m * 16) * N_DIM + col;
      po[0]                 = acc[m][n][0] + bv;
      po[(size_t)N_DIM]     = acc[m][n][1] + bv;
      po[2 * (size_t)N_DIM] = acc[m][n][2] + bv;
      po[3 * (size_t)N_DIM] = acc[m][n][3] + bv;
    }
  }
}

extern "C" void kernel_launch(void* const* d_in, const int* in_sizes, int n_in,
                              void* d_out, int out_size, void* d_ws, size_t ws_size,
                              hipStream_t stream) {
  const float* x    = (const float*)d_in[0];
  const int* qw     = (const int*)d_in[1];
  const int* qz     = (const int*)d_in[2];
  const float* sc   = (const float*)d_in[3];
  const float* bias = (const float*)d_in[4];
  float* out = (float*)d_out;

  const int M = in_sizes[0] / K_DIM;        // 2048
  const int Mblk = M / 128;                 // 16
  const int grid = Mblk * (N_DIM / 128);    // 1376 (divisible by 8)

  __bf16* Wt = (__bf16*)d_ws;               // 90MB dequantized weights

  dequant_kernel<<<(K_DIM / 64) * (N_DIM / 64), 256, 0, stream>>>(qw, qz, sc, Wt);

  wq_gemm_kernel<<<grid, 256, 0, stream>>>(x, Wt, bias, out, Mblk);
}

// Round 13
// 239.869 us; speedup vs baseline: 1.9414x; 1.9414x over previous
//
#include <hip/hip_runtime.h>
#include <stdint.h>

#define K_DIM 4096
#define N_DIM 11008
#define NCOL  1376   // N/8

typedef __attribute__((ext_vector_type(4))) float  f32x4;
typedef __attribute__((ext_vector_type(8))) __bf16 bf16x8;

__device__ __forceinline__ void gload_lds16(const void* g, void* l) {
  __builtin_amdgcn_global_load_lds((const __attribute__((address_space(1))) void*)g,
                                   (__attribute__((address_space(3))) void*)l,
                                   16, 0, 0);
}

// ---------- prologue 1: x fp32 -> bf16 (load-bearing: halves A stream, R12 proved) ----------
__global__ void __launch_bounds__(256) convert_x_kernel(const float* __restrict__ x,
                                                        __bf16* __restrict__ a) {
  size_t i = ((size_t)blockIdx.x * 256u + threadIdx.x) * 8u;
  f32x4 v0 = *(const f32x4*)(x + i);
  f32x4 v1 = *(const f32x4*)(x + i + 4);
  bf16x8 o;
  o[0] = (__bf16)v0[0]; o[1] = (__bf16)v0[1]; o[2] = (__bf16)v0[2]; o[3] = (__bf16)v0[3];
  o[4] = (__bf16)v1[0]; o[5] = (__bf16)v1[1]; o[6] = (__bf16)v1[2]; o[7] = (__bf16)v1[3];
  *(bf16x8*)(a + i) = o;
}

// ---------- prologue 2: AWQ dequant -> Wt bf16 [N][K] (transposed via LDS) ----------
__global__ void __launch_bounds__(256) dequant_kernel(const int* __restrict__ qw,
                                                      const int* __restrict__ qz,
                                                      const float* __restrict__ sc,
                                                      __bf16* __restrict__ wt) {
  constexpr int SH[8] = {0, 16, 4, 20, 8, 24, 12, 28};  // AWQ [0,4,1,5,2,6,3,7]*4
  __shared__ __bf16 tile[64][72];
  const int bid = blockIdx.x;
  const int tk = bid & 63;
  const int tn = bid >> 6;
  const int k0 = tk * 64;
  const int c0 = tn * 8;
  const int t = threadIdx.x;
#pragma unroll
  for (int r = 0; r < 2; ++r) {
    int idx = r * 256 + t;
    int kk = idx >> 3;
    int cc = idx & 7;
    int k = k0 + kk;
    int c = c0 + cc;
    uint32_t q  = (uint32_t)qw[(size_t)k * NCOL + c];
    int g = k >> 7;
    uint32_t zq = (uint32_t)qz[(size_t)g * NCOL + c];
    const float* s = sc + (size_t)g * N_DIM + (size_t)c * 8;
#pragma unroll
    for (int j = 0; j < 8; ++j) {
      int wv = (int)((q >> SH[j]) & 15u) - (int)((zq >> SH[j]) & 15u);
      tile[cc * 8 + j][kk] = (__bf16)((float)wv * s[j]);
    }
  }
  __syncthreads();
  const int n0 = tn * 64;
#pragma unroll
  for (int r = 0; r < 2; ++r) {
    int idx = r * 256 + t;
    int row = idx >> 3;
    int kc = idx & 7;
    bf16x8 v = *(const bf16x8*)&tile[row][kc * 8];
    *(bf16x8*)(wt + (size_t)(n0 + row) * K_DIM + k0 + kc * 8) = v;
  }
}

// ---------- main GEMM: 128x128 tile, BK=64, DOUBLE-BUFFERED single-barrier ----------
// R7 chassis (bf16 Aw + Wt from ws; gload_lds DMA staging; granule-XOR swizzle,
// 0 conflicts R1-R12; verified fragment/epilogue maps).
// The one untested structural cell: dbuf at FULL tile granularity.
//   R10 (dbuf, BK=32, 12 waves): 37.7% steady -- too fine.
//   R4  (2-barrier, 8 waves):    54.6% steady -- best steady measured.
//   This (dbuf, BK=64, 8 waves): one barrier/K-tile, 32 MFMA/wave/barrier,
//   drain covers loads issued a full compute-tile (~400cy) earlier, 2 resident
//   blocks backfill each other's drains.
// Loop: { stage(t+1 -> buf^1); ds_read+MFMA(buf); __syncthreads(); }
// Race-free: barrier at end of t-1 completes all reads of buf^1 before t's DMA
// overwrites it; the barrier's implicit vmcnt(0) makes t+1's tile visible.
// LDS 2 x (A 16KB + B 16KB) = 64KB static -> exactly 2 blk/CU; 8 waves/CU;
// eff = 1376/(3*512) = 0.896.
__global__ void __launch_bounds__(256, 2) wq_gemm_kernel(
    const __bf16* __restrict__ A,    // [M][K] bf16
    const __bf16* __restrict__ Wt,   // [N][K] bf16
    const float* __restrict__ bias,
    float* __restrict__ out,
    const int Mblk)
{
  __shared__ char lds[65536];   // buf b at b*32768: A [0:16K), B [16K:32K)

  const int nwg = gridDim.x;
  int bid = blockIdx.x;
  if ((nwg & 7) == 0) {                 // XCD-aware swizzle (1376 % 8 == 0, bijective)
    const int cpx = nwg >> 3;
    bid = (bid & 7) * cpx + (bid >> 3);
  }
  const int bm = bid % Mblk;            // m-fastest: XCD chunk reuses B panels in L2
  const int bn = bid / Mblk;
  const int m0 = bm * 128;
  const int n0 = bn * 128;

  const int t = threadIdx.x;
  const int lane = t & 63;
  const int w = t >> 6;      // 0..3
  const int wr = w >> 1;     // 0..1  (M half)
  const int wc = w & 1;      // 0..1  (N half)
  const int lrow = lane & 15;
  const int lk = lane >> 4;

  // staging (R7-verified): round i covers rows i*32..i*32+31; source granule
  // gl = (t&7)^((t>>3)&7) (i-independent); dest = linear cid*16.
  const int gl = (t & 7) ^ ((t >> 3) & 7);
  const uint32_t off0 = (uint32_t)(t >> 3) * K_DIM + (uint32_t)gl * 8;
  const __bf16* pA = A  + (size_t)m0 * K_DIM + off0;
  const __bf16* pB = Wt + (size_t)n0 * K_DIM + off0;
  const int w1024 = w * 1024;

#define STAGE_TILE(BUF, KOFF) do { \
    char* _b = (BUF); \
    _Pragma("unroll") \
    for (int _i = 0; _i < 4; ++_i) { \
      gload_lds16(pA + (KOFF) + (size_t)_i * (32 * K_DIM), _b + _i * 4096 + w1024); \
      gload_lds16(pB + (KOFF) + (size_t)_i * (32 * K_DIM), _b + 16384 + _i * 4096 + w1024); \
    } } while (0)

  f32x4 acc[4][4];
#pragma unroll
  for (int i = 0; i < 4; ++i)
#pragma unroll
    for (int j = 0; j < 4; ++j) acc[i][j] = (f32x4){0.f, 0.f, 0.f, 0.f};

  // compute-side bases (R7-verified; row&7 == lrow&7)
  const int abase_off = (wr * 64 + lrow) * 128;
  const int bbase_off = 16384 + (wc * 64 + lrow) * 128;
  const int gk0 = (lk ^ (lrow & 7)) << 4;        // kk=0 granule byte offset
  const int gk1 = ((4 + lk) ^ (lrow & 7)) << 4;  // kk=1

  // prologue: stage tile 0 into buf 0
  STAGE_TILE(lds, 0u);
  __syncthreads();

  for (int kt = 0; kt < 64; ++kt) {
    char* curb = lds + (kt & 1) * 32768;
    if (kt < 63) {
      char* nxtb = lds + ((kt + 1) & 1) * 32768;
      STAGE_TILE(nxtb, (uint32_t)(kt + 1) * 64);
    }
    __builtin_amdgcn_sched_barrier(0);   // stage issues stay ahead of compute

    const char* ab = curb + abase_off;
    const char* bb = curb + bbase_off;
#pragma unroll
    for (int kk = 0; kk < 2; ++kk) {
      const int g = kk ? gk1 : gk0;
      bf16x8 av[4], bv[4];
#pragma unroll
      for (int m = 0; m < 4; ++m) av[m] = *(const bf16x8*)(ab + m * 2048 + g);
#pragma unroll
      for (int n = 0; n < 4; ++n) bv[n] = *(const bf16x8*)(bb + n * 2048 + g);
#pragma unroll
      for (int m = 0; m < 4; ++m)
#pragma unroll
        for (int n = 0; n < 4; ++n)
          acc[m][n] = __builtin_amdgcn_mfma_f32_16x16x32_bf16(av[m], bv[n], acc[m][n], 0, 0, 0);
    }

    __syncthreads();   // one barrier/K-tile: drains next tile's DMA (issued ~400cy ago)
  }
#undef STAGE_TILE

  // epilogue: C/D layout col=lane&15, row=(lane>>4)*4+reg (m89-verified, R1-R12-passed)
  const int orow0 = m0 + wr * 64 + lk * 4;
  const int ocol0 = n0 + wc * 64 + lrow;
#pragma unroll
  for (int n = 0; n < 4; ++n) {
    const int col = ocol0 + n * 16;
    const float bv = bias[col];
#pragma unroll
    for (int m = 0; m < 4; ++m) {
      float* po = out + (size_t)(orow0 + m * 16) * N_DIM + col;
      po[0]                 = acc[m][n][0] + bv;
      po[(size_t)N_DIM]     = acc[m][n][1] + bv;
      po[2 * (size_t)N_DIM] = acc[m][n][2] + bv;
      po[3 * (size_t)N_DIM] = acc[m][n][3] + bv;
    }
  }
}

extern "C" void kernel_launch(void* const* d_in, const int* in_sizes, int n_in,
                              void* d_out, int out_size, void* d_ws, size_t ws_size,
                              hipStream_t stream) {
  const float* x    = (const float*)d_in[0];
  const int* qw     = (const int*)d_in[1];
  const int* qz     = (const int*)d_in[2];
  const float* sc   = (const float*)d_in[3];
  const float* bias = (const float*)d_in[4];
  float* out = (float*)d_out;

  const int M = in_sizes[0] / K_DIM;        // 2048
  const int Mblk = M / 128;                 // 16
  const int grid = Mblk * (N_DIM / 128);    // 1376 (divisible by 8)

  const size_t abytes = (size_t)M * K_DIM * 2;
  __bf16* Aw = (__bf16*)d_ws;
  __bf16* Wt = (__bf16*)((char*)d_ws + abytes);

  convert_x_kernel<<<(M * K_DIM) / 2048, 256, 0, stream>>>(x, Aw);
  dequant_kernel<<<(K_DIM / 64) * (N_DIM / 64), 256, 0, stream>>>(qw, qz, sc, Wt);

  wq_gemm_kernel<<<grid, 256, 0, stream>>>(Aw, Wt, bias, out, Mblk);
}

// Round 14
// 226.656 us; speedup vs baseline: 2.0545x; 1.0583x over previous
//
#include <hip/hip_runtime.h>
#include <stdint.h>

#define K_DIM 4096
#define N_DIM 11008
#define NCOL  1376   // N/8

typedef __attribute__((ext_vector_type(4))) float  f32x4;
typedef __attribute__((ext_vector_type(8))) __bf16 bf16x8;

__device__ __forceinline__ void gload_lds16(const void* g, void* l) {
  __builtin_amdgcn_global_load_lds((const __attribute__((address_space(1))) void*)g,
                                   (__attribute__((address_space(3))) void*)l,
                                   16, 0, 0);
}

// ---------- fused prologue: convert x (blocks [0,nconv)) + AWQ dequant (rest) ----------
// Both bodies verbatim from the R1-R13-verified standalone kernels; fusing
// saves one launch gap. Both are HBM-BW-bound (~26us combined floor).
__global__ void __launch_bounds__(256) prologue_kernel(
    const float* __restrict__ x, __bf16* __restrict__ a,
    const int* __restrict__ qw, const int* __restrict__ qz,
    const float* __restrict__ sc, __bf16* __restrict__ wt, const int nconv) {
  __shared__ __bf16 tile[64][72];
  if ((int)blockIdx.x < nconv) {
    // ---- convert: x fp32 -> bf16 (load-bearing: halves A stream, R12 proved) ----
    size_t i = ((size_t)blockIdx.x * 256u + threadIdx.x) * 8u;
    f32x4 v0 = *(const f32x4*)(x + i);
    f32x4 v1 = *(const f32x4*)(x + i + 4);
    bf16x8 o;
    o[0] = (__bf16)v0[0]; o[1] = (__bf16)v0[1]; o[2] = (__bf16)v0[2]; o[3] = (__bf16)v0[3];
    o[4] = (__bf16)v1[0]; o[5] = (__bf16)v1[1]; o[6] = (__bf16)v1[2]; o[7] = (__bf16)v1[3];
    *(bf16x8*)(a + i) = o;
    return;
  }
  // ---- dequant: qweight -> Wt bf16 [N][K] (transposed via LDS) ----
  constexpr int SH[8] = {0, 16, 4, 20, 8, 24, 12, 28};  // AWQ [0,4,1,5,2,6,3,7]*4
  const int bid = blockIdx.x - nconv;
  const int tk = bid & 63;
  const int tn = bid >> 6;
  const int k0 = tk * 64;
  const int c0 = tn * 8;
  const int t = threadIdx.x;
#pragma unroll
  for (int r = 0; r < 2; ++r) {
    int idx = r * 256 + t;
    int kk = idx >> 3;
    int cc = idx & 7;
    int k = k0 + kk;
    int c = c0 + cc;
    uint32_t q  = (uint32_t)qw[(size_t)k * NCOL + c];
    int g = k >> 7;
    uint32_t zq = (uint32_t)qz[(size_t)g * NCOL + c];
    const float* s = sc + (size_t)g * N_DIM + (size_t)c * 8;
#pragma unroll
    for (int j = 0; j < 8; ++j) {
      int wv = (int)((q >> SH[j]) & 15u) - (int)((zq >> SH[j]) & 15u);
      tile[cc * 8 + j][kk] = (__bf16)((float)wv * s[j]);
    }
  }
  __syncthreads();
  const int n0 = tn * 64;
#pragma unroll
  for (int r = 0; r < 2; ++r) {
    int idx = r * 256 + t;
    int row = idx >> 3;
    int kc = idx & 7;
    bf16x8 v = *(const bf16x8*)&tile[row][kc * 8];
    *(bf16x8*)(wt + (size_t)(n0 + row) * K_DIM + k0 + kc * 8) = v;
  }
}

// ---------- main GEMM: 128x128 tile, BK=64 — R7 chassis (best measured, verbatim) ----------
// 4 waves (2M x 2N), per-wave 64x64 = 4x4 frags of 16x16x32 bf16 MFMA.
// Structural plateau (R1-R13 sweep): avg MfmaUtil = steady(waves/CU) x
// eff(grid) <= max(0.672x64%, 0.896x48%) ~ 43%; N = 43x256 makes the two
// terms jointly unimprovable. This config: 48KB dynamic LDS (32KB used) caps
// residency at 3 blk/CU -> eff 0.896 with 12 waves/CU barrier hiding.
// Granule-XOR swizzle (0 conflicts R1-R13): row r, granule g at physical
// g^(r&7); linear gload dest + inverse-swizzled global source (rule #21).
__global__ void __launch_bounds__(256, 3) wq_gemm_kernel(
    const __bf16* __restrict__ A,    // [M][K] bf16
    const __bf16* __restrict__ Wt,   // [N][K] bf16
    const float* __restrict__ bias,
    float* __restrict__ out,
    const int Mblk)
{
  extern __shared__ char lds[];      // 49152 allocated; As = lds[0:16K), Bs = [16K:32K)
  char* As = lds;
  char* Bs = lds + 16384;

  const int nwg = gridDim.x;
  int bid = blockIdx.x;
  if ((nwg & 7) == 0) {                 // XCD-aware swizzle (1376 % 8 == 0, bijective)
    const int cpx = nwg >> 3;
    bid = (bid & 7) * cpx + (bid >> 3);
  }
  const int bm = bid % Mblk;            // m-fastest: XCD chunk reuses B panels in L2
  const int bn = bid / Mblk;
  const int m0 = bm * 128;
  const int n0 = bn * 128;

  const int t = threadIdx.x;
  const int lane = t & 63;
  const int w = t >> 6;      // 0..3
  const int wr = w >> 1;     // 0..1  (M half)
  const int wc = w & 1;      // 0..1  (N half)
  const int lrow = lane & 15;
  const int lk = lane >> 4;

  // staging: round i, cid = i*256+t; rp = cid>>3 (0..127),
  // gl = (cid&7)^(rp&7) (inverse-swizzled source granule); dest = cid*16 linear
  const int gl = (t & 7) ^ ((t >> 3) & 7);
  const uint32_t off0 = (uint32_t)(t >> 3) * K_DIM + (uint32_t)gl * 8;
  const __bf16* pA = A  + (size_t)m0 * K_DIM + off0;
  const __bf16* pB = Wt + (size_t)n0 * K_DIM + off0;
  const int w1024 = w * 1024;

  f32x4 acc[4][4];
#pragma unroll
  for (int i = 0; i < 4; ++i)
#pragma unroll
    for (int j = 0; j < 4; ++j) acc[i][j] = (f32x4){0.f, 0.f, 0.f, 0.f};

  // compute-side bases (row&7 == lrow&7 since frag row strides are multiples of 16)
  const char* abase = As + (wr * 64 + lrow) * 128;
  const char* bbase = Bs + (wc * 64 + lrow) * 128;
  const int gk0 = (lk ^ (lrow & 7)) << 4;        // kk=0 granule byte offset
  const int gk1 = ((4 + lk) ^ (lrow & 7)) << 4;  // kk=1

  for (int kt = 0; kt < 64; ++kt) {
    __syncthreads();   // previous tile's compute done; LDS reusable
#pragma unroll
    for (int i = 0; i < 4; ++i)    // A: 4 rounds (rows 32i .. 32i+31)
      gload_lds16(pA + (size_t)i * (32 * K_DIM), As + i * 4096 + w1024);
#pragma unroll
    for (int i = 0; i < 4; ++i)    // B: 4 rounds
      gload_lds16(pB + (size_t)i * (32 * K_DIM), Bs + i * 4096 + w1024);
    pA += 64; pB += 64;
    __syncthreads();   // compiler drains vmcnt(0): staged tile visible

#pragma unroll
    for (int kk = 0; kk < 2; ++kk) {
      const int g = kk ? gk1 : gk0;
      bf16x8 av[4], bv[4];
#pragma unroll
      for (int m = 0; m < 4; ++m) av[m] = *(const bf16x8*)(abase + m * 2048 + g);
#pragma unroll
      for (int n = 0; n < 4; ++n) bv[n] = *(const bf16x8*)(bbase + n * 2048 + g);
#pragma unroll
      for (int m = 0; m < 4; ++m)
#pragma unroll
        for (int n = 0; n < 4; ++n)
          acc[m][n] = __builtin_amdgcn_mfma_f32_16x16x32_bf16(av[m], bv[n], acc[m][n], 0, 0, 0);
    }
  }

  // epilogue: C/D layout col=lane&15, row=(lane>>4)*4+reg (m89-verified, R1-R13-passed)
  const int orow0 = m0 + wr * 64 + lk * 4;
  const int ocol0 = n0 + wc * 64 + lrow;
#pragma unroll
  for (int n = 0; n < 4; ++n) {
    const int col = ocol0 + n * 16;
    const float bv = bias[col];
#pragma unroll
    for (int m = 0; m < 4; ++m) {
      float* po = out + (size_t)(orow0 + m * 16) * N_DIM + col;
      po[0]                 = acc[m][n][0] + bv;
      po[(size_t)N_DIM]     = acc[m][n][1] + bv;
      po[2 * (size_t)N_DIM] = acc[m][n][2] + bv;
      po[3 * (size_t)N_DIM] = acc[m][n][3] + bv;
    }
  }
}

extern "C" void kernel_launch(void* const* d_in, const int* in_sizes, int n_in,
                              void* d_out, int out_size, void* d_ws, size_t ws_size,
                              hipStream_t stream) {
  const float* x    = (const float*)d_in[0];
  const int* qw     = (const int*)d_in[1];
  const int* qz     = (const int*)d_in[2];
  const float* sc   = (const float*)d_in[3];
  const float* bias = (const float*)d_in[4];
  float* out = (float*)d_out;

  const int M = in_sizes[0] / K_DIM;        // 2048
  const int Mblk = M / 128;                 // 16
  const int grid = Mblk * (N_DIM / 128);    // 1376 (divisible by 8)

  const size_t abytes = (size_t)M * K_DIM * 2;
  __bf16* Aw = (__bf16*)d_ws;
  __bf16* Wt = (__bf16*)((char*)d_ws + abytes);

  const int nconv = (M * K_DIM) / 2048;                      // 4096 convert blocks
  const int ndeq  = (K_DIM / 64) * (N_DIM / 64);             // 11008 dequant blocks
  prologue_kernel<<<nconv + ndeq, 256, 0, stream>>>(x, Aw, qw, qz, sc, Wt, nconv);

  hipFuncSetAttribute((const void*)wq_gemm_kernel,
                      hipFuncAttributeMaxDynamicSharedMemorySize, 49152);
  // 48KB dynamic LDS (32KB used): caps residency at 3 blocks/CU -> the
  // 1376-block grid runs at eff 0.896 with 12 waves/CU for barrier hiding.
  wq_gemm_kernel<<<grid, 256, 49152, stream>>>(Aw, Wt, bias, out, Mblk);
}